// Round 3
// baseline (140.154 us; speedup 1.0000x reference)
//
#include <hip/hip_runtime.h>

// LocalConnectivity: diamond (L1-ball radius 5) circular convolution over
// (B=64, H=512, W=512) fp32, weight per L1-distance d: w_d = d_in[1][d-1].
//
// Decomposition (exact):
//   h_a[r][j] = sum_{|b| <= 5-a} w_{a+|b|} * s[r][(j+b)&511]   (h_0 excludes b=0)
//   out[i][j] = h_0[i][j] + sum_{a=1..5} (h_a[i-a][j] + h_a[i+a][j])
//
// R1: forced 64-VGPR cap on 124-reg kernel -> spills -> 217 us.
// R2: direct global reads: 67 us, latency-bound.
// R3: LDS pipeline, 128thr x 4col, b128 reads: 43.4 us. VGPR=124, barrier-
//     latency-bound (VALU 22%, HBM 35%).
// R4 FAILED: 256thr x 2col + __launch_bounds__(256,8): allocator collapse
//     (VGPR=32) + scratch spills (WRITE 65->403 MB), 157 us. Never force.
// R5: 512thr x 1col, global_load_lds staging: VGPR=20, occ 55%, 49 us.
//     LDS-ISSUE-BOUND: 11 scalar ds_read_b32/thr-iter = 510 LDS cyc per
//     block-iter -> 44 us floor == observed. Scalar reads are the disease.
// R6 (this): 256thr x 2col. Halo via 7 x ds_read_b64 (168 LDS cyc/block-iter
//     -> 14.6 us floor). acc[11][2]=22 regs, est live ~55 -> <=64 naturally.
//     __syncthreads (vmcnt(0) drain = 1-deep pipeline) replaced with counted
//     s_waitcnt vmcnt(2) + raw s_barrier (T3/T4, m201 precedent): row rr's
//     loads drained before barrier rr, rows rr+1/rr+2 stay in flight ->
//     2-iter latency cover. Hazards: slot (rr+2)%6 occupant row rr-4 last
//     read before barrier rr-3 < barrier rr; per-wave vmcnt drain before
//     barrier makes staged data globally visible. Tail iter uses vmcnt(0).

#define LC_H 512
#define LC_W 512
#define LC_TY 16
#define LC_NT 256   // threads per block; each owns 2 columns
#define LC_NR (LC_TY + 10)  // 26 source rows per strip
#define LC_RS 6     // LDS ring slots

typedef const __attribute__((address_space(1))) void* lc_gvp;
typedef __attribute__((address_space(3))) void* lc_lvp;

__global__ __launch_bounds__(LC_NT)
void LocalConnectivity_kernel(const float* __restrict__ in,
                              const float* __restrict__ wp,
                              float* __restrict__ out) {
    const int t = threadIdx.x;            // column-pair index 0..255
    const int b = blockIdx.y;             // batch
    const int r0 = blockIdx.x * LC_TY;    // first output row of strip

    const float w1 = wp[0], w2 = wp[1], w3 = wp[2], w4 = wp[3], w5 = wp[4];

    const float* __restrict__ src = in + (size_t)b * (LC_H * LC_W);
    float* __restrict__ dst = out + (size_t)b * (LC_H * LC_W);

    __shared__ __attribute__((aligned(16))) float lds[LC_RS * LC_W]; // 12 KB

    // async DMA of source row j (grid row (r0+j-5)&511) into slot j%6.
    // 256 threads x 2 size-4 issues: lane-contiguous LDS dests per wave.
#define LC_ISSUE(j) do {                                                     \
        const float* rp_ = src + ((r0 + (j) - 5) & (LC_H - 1)) * LC_W;       \
        float* lp_ = &lds[((j) % LC_RS) * LC_W];                             \
        __builtin_amdgcn_global_load_lds((lc_gvp)(rp_ + t),                  \
                                         (lc_lvp)(lp_ + t), 4, 0, 0);        \
        __builtin_amdgcn_global_load_lds((lc_gvp)(rp_ + LC_NT + t),          \
                                         (lc_lvp)(lp_ + LC_NT + t), 4, 0, 0);\
    } while (0)

    float acc[11][2];
#pragma unroll
    for (int k = 0; k < 11; ++k) { acc[k][0] = 0.f; acc[k][1] = 0.f; }

    // pipeline prologue: rows 0,1 in flight (2 loads each)
    LC_ISSUE(0);
    LC_ISSUE(1);

#pragma unroll
    for (int rr = 0; rr < LC_NR; ++rr) {
        // Drain MY row-rr loads (allow rows rr+1.. to stay in flight), then
        // barrier: all waves' row-rr data is in LDS. Compiler fence stops
        // LDS reads from hoisting above the barrier.
        if (rr + 1 < LC_NR) {
            asm volatile("s_waitcnt vmcnt(2)" ::: "memory");
        } else {
            asm volatile("s_waitcnt vmcnt(0)" ::: "memory");
        }
        __builtin_amdgcn_s_barrier();
        asm volatile("" ::: "memory");

        // prefetch row rr+2 into slot (rr+2)%6 (2-iter flight time)
        if (rr + 2 < LC_NR) LC_ISSUE(rr + 2);

        // halo cols 2t-6 .. 2t+7 of source row rr: 7 x ds_read_b64
        const float* slotp = &lds[(rr % LC_RS) * LC_W];
        float v[14];
#pragma unroll
        for (int o = 0; o < 7; ++o) {
            const int cb = (t + o - 3) & (LC_NT - 1);
            const float2 f = *reinterpret_cast<const float2*>(slotp + cb * 2);
            v[o * 2 + 0] = f.x;
            v[o * 2 + 1] = f.y;
        }

        // horizontal pass + vertical scatter fused: v[6+q] is my column q
        // (global 2t+q). r_off is compile-time per unrolled iter -> guards
        // and %11 ring indices fold; acc stays in named registers.
        const int r_off = rr - 5;
#pragma unroll
        for (int q = 0; q < 2; ++q) {
            const float p0 = v[6 + q];
            const float p1 = v[5 + q] + v[7 + q];
            const float p2 = v[4 + q] + v[8 + q];
            const float p3 = v[3 + q] + v[9 + q];
            const float p4 = v[2 + q] + v[10 + q];
            const float p5 = v[1 + q] + v[11 + q];

            float hv;
            hv = w1 * p1 + w2 * p2 + w3 * p3 + w4 * p4 + w5 * p5;
            if (r_off >= 0 && r_off < LC_TY) acc[r_off % 11][q] += hv;
            hv = w1 * p0 + w2 * p1 + w3 * p2 + w4 * p3 + w5 * p4;
            {
                const int op = r_off + 1, om = r_off - 1;
                if (op >= 0 && op < LC_TY) acc[op % 11][q] += hv;
                if (om >= 0 && om < LC_TY) acc[om % 11][q] += hv;
            }
            hv = w2 * p0 + w3 * p1 + w4 * p2 + w5 * p3;
            {
                const int op = r_off + 2, om = r_off - 2;
                if (op >= 0 && op < LC_TY) acc[op % 11][q] += hv;
                if (om >= 0 && om < LC_TY) acc[om % 11][q] += hv;
            }
            hv = w3 * p0 + w4 * p1 + w5 * p2;
            {
                const int op = r_off + 3, om = r_off - 3;
                if (op >= 0 && op < LC_TY) acc[op % 11][q] += hv;
                if (om >= 0 && om < LC_TY) acc[om % 11][q] += hv;
            }
            hv = w4 * p0 + w5 * p1;
            {
                const int op = r_off + 4, om = r_off - 4;
                if (op >= 0 && op < LC_TY) acc[op % 11][q] += hv;
                if (om >= 0 && om < LC_TY) acc[om % 11][q] += hv;
            }
            hv = w5 * p0;
            {
                const int op = r_off + 5, om = r_off - 5;
                if (op >= 0 && op < LC_TY) acc[op % 11][q] += hv;
                if (om >= 0 && om < LC_TY) acc[om % 11][q] += hv;
            }
        }

        // output row oc = rr - 10 complete after this source row
        const int oc = rr - 10;
        if (oc >= 0 && oc < LC_TY) {
            const int slot = oc % 11;
            float2 f;
            f.x = acc[slot][0];
            f.y = acc[slot][1];
            *reinterpret_cast<float2*>(dst + (size_t)(r0 + oc) * LC_W + t * 2) = f;
            acc[slot][0] = 0.f;
            acc[slot][1] = 0.f;
        }
    }
#undef LC_ISSUE
}

extern "C" void kernel_launch(void* const* d_in, const int* in_sizes, int n_in,
                              void* d_out, int out_size, void* d_ws, size_t ws_size,
                              hipStream_t stream) {
    const float* grid_spikes = (const float*)d_in[0];       // 64*512*512 fp32
    const float* distance_weights = (const float*)d_in[1];  // 5 fp32
    float* out = (float*)d_out;

    dim3 grid(LC_H / LC_TY, 64);  // 32 strips x 64 batches
    dim3 block(LC_NT);
    LocalConnectivity_kernel<<<grid, block, 0, stream>>>(grid_spikes, distance_weights, out);
}

// Round 4
// 119.822 us; speedup vs baseline: 1.1697x; 1.1697x over previous
//
#include <hip/hip_runtime.h>

// LocalConnectivity: diamond (L1-ball radius 5) circular convolution over
// (B=64, H=512, W=512) fp32, weight per L1-distance d: w_d = d_in[1][d-1].
//
// Decomposition (exact):
//   h_a[r][j] = sum_{|b| <= 5-a} w_{a+|b|} * s[r][(j+b)&511]   (h_0 excludes b=0)
//   out[i][j] = h_0[i][j] + sum_{a=1..5} (h_a[i-a][j] + h_a[i+a][j])
//
// R1: forced 64-VGPR cap on 124-reg kernel -> spills -> 217 us.
// R2: direct global reads: 67 us, latency-bound.
// R3: LDS 6-slot ring, 128thr x 4col: 43.4 us. VGPR=124.
// R4 FAILED: forced __launch_bounds__(256,8) -> spills, 157 us. Never force.
// R5: 512thr x 1col: VGPR=20, 49 us. LDS-issue-bound (11 scalar b32 reads).
// R6: 256thr x 2col, 7x ds_read_b64, counted vmcnt(2)+barrier: 54 us.
//   KEY CROSS-ROUND FINDING: resident blocks/CU ~= 2.3 in R3/R5/R6 alike;
//   per-iter barrier+wait = 26 latency-exposed stalls/block (~1340 cyc/iter
//   observed == one HBM latency each). Pipelining depth tweaks can't fix a
//   structure with a barrier every ~300 compute-cycles.
// R7 (this): ONE barrier per block. Stage the whole 26-row strip (52 KB LDS,
//   3 blocks/CU) via 52 back-to-back global_load_lds (52 outstanding/wave,
//   single amortized latency stall), one __syncthreads, then 26 compute
//   iterations with no barriers/waits (LDS read-only afterwards). Compute
//   body identical to R6's verified one. Floors: HBM 19.4 us, LDS-pipe
//   ~15 us, VALU ~14 us.

#define LC_H 512
#define LC_W 512
#define LC_TY 16
#define LC_NT 256   // threads per block; each owns 2 columns
#define LC_NR (LC_TY + 10)  // 26 source rows per strip
// LDS: 26 rows x 512 f32 = 53248 B -> 3 blocks/CU

typedef const __attribute__((address_space(1))) void* lc_gvp;
typedef __attribute__((address_space(3))) void* lc_lvp;

__global__ __launch_bounds__(LC_NT)
void LocalConnectivity_kernel(const float* __restrict__ in,
                              const float* __restrict__ wp,
                              float* __restrict__ out) {
    const int t = threadIdx.x;            // column-pair index 0..255
    const int b = blockIdx.y;             // batch
    const int r0 = blockIdx.x * LC_TY;    // first output row of strip

    const float w1 = wp[0], w2 = wp[1], w3 = wp[2], w4 = wp[3], w5 = wp[4];

    const float* __restrict__ src = in + (size_t)b * (LC_H * LC_W);
    float* __restrict__ dst = out + (size_t)b * (LC_H * LC_W);

    __shared__ __attribute__((aligned(16))) float lds[LC_NR * LC_W]; // 52 KB

    // ---- stage the full strip: source row j -> LDS row j, 2 DMA insts each.
    // All 52 issued back-to-back: one latency stall per block, not per row.
#pragma unroll
    for (int j = 0; j < LC_NR; ++j) {
        const float* rp = src + ((r0 + j - 5) & (LC_H - 1)) * LC_W;
        float* lp = &lds[j * LC_W];
        __builtin_amdgcn_global_load_lds((lc_gvp)(rp + t),
                                         (lc_lvp)(lp + t), 4, 0, 0);
        __builtin_amdgcn_global_load_lds((lc_gvp)(rp + LC_NT + t),
                                         (lc_lvp)(lp + LC_NT + t), 4, 0, 0);
    }

    float acc[11][2];
#pragma unroll
    for (int k = 0; k < 11; ++k) { acc[k][0] = 0.f; acc[k][1] = 0.f; }

    __syncthreads();   // drains vmcnt(0): whole strip visible; only barrier.

#pragma unroll
    for (int rr = 0; rr < LC_NR; ++rr) {
        // halo cols 2t-6 .. 2t+7 of source row rr: 7 x ds_read_b64
        const float* slotp = &lds[rr * LC_W];
        float v[14];
#pragma unroll
        for (int o = 0; o < 7; ++o) {
            const int cb = (t + o - 3) & (LC_NT - 1);
            const float2 f = *reinterpret_cast<const float2*>(slotp + cb * 2);
            v[o * 2 + 0] = f.x;
            v[o * 2 + 1] = f.y;
        }

        // horizontal pass + vertical scatter fused: v[6+q] is my column q
        // (global 2t+q). r_off is compile-time per unrolled iter -> guards
        // and %11 ring indices fold; acc stays in named registers.
        const int r_off = rr - 5;
#pragma unroll
        for (int q = 0; q < 2; ++q) {
            const float p0 = v[6 + q];
            const float p1 = v[5 + q] + v[7 + q];
            const float p2 = v[4 + q] + v[8 + q];
            const float p3 = v[3 + q] + v[9 + q];
            const float p4 = v[2 + q] + v[10 + q];
            const float p5 = v[1 + q] + v[11 + q];

            float hv;
            hv = w1 * p1 + w2 * p2 + w3 * p3 + w4 * p4 + w5 * p5;
            if (r_off >= 0 && r_off < LC_TY) acc[r_off % 11][q] += hv;
            hv = w1 * p0 + w2 * p1 + w3 * p2 + w4 * p3 + w5 * p4;
            {
                const int op = r_off + 1, om = r_off - 1;
                if (op >= 0 && op < LC_TY) acc[op % 11][q] += hv;
                if (om >= 0 && om < LC_TY) acc[om % 11][q] += hv;
            }
            hv = w2 * p0 + w3 * p1 + w4 * p2 + w5 * p3;
            {
                const int op = r_off + 2, om = r_off - 2;
                if (op >= 0 && op < LC_TY) acc[op % 11][q] += hv;
                if (om >= 0 && om < LC_TY) acc[om % 11][q] += hv;
            }
            hv = w3 * p0 + w4 * p1 + w5 * p2;
            {
                const int op = r_off + 3, om = r_off - 3;
                if (op >= 0 && op < LC_TY) acc[op % 11][q] += hv;
                if (om >= 0 && om < LC_TY) acc[om % 11][q] += hv;
            }
            hv = w4 * p0 + w5 * p1;
            {
                const int op = r_off + 4, om = r_off - 4;
                if (op >= 0 && op < LC_TY) acc[op % 11][q] += hv;
                if (om >= 0 && om < LC_TY) acc[om % 11][q] += hv;
            }
            hv = w5 * p0;
            {
                const int op = r_off + 5, om = r_off - 5;
                if (op >= 0 && op < LC_TY) acc[op % 11][q] += hv;
                if (om >= 0 && om < LC_TY) acc[om % 11][q] += hv;
            }
        }

        // output row oc = rr - 10 complete after this source row
        const int oc = rr - 10;
        if (oc >= 0 && oc < LC_TY) {
            const int slot = oc % 11;
            float2 f;
            f.x = acc[slot][0];
            f.y = acc[slot][1];
            *reinterpret_cast<float2*>(dst + (size_t)(r0 + oc) * LC_W + t * 2) = f;
            acc[slot][0] = 0.f;
            acc[slot][1] = 0.f;
        }
    }
}

extern "C" void kernel_launch(void* const* d_in, const int* in_sizes, int n_in,
                              void* d_out, int out_size, void* d_ws, size_t ws_size,
                              hipStream_t stream) {
    const float* grid_spikes = (const float*)d_in[0];       // 64*512*512 fp32
    const float* distance_weights = (const float*)d_in[1];  // 5 fp32
    float* out = (float*)d_out;

    dim3 grid(LC_H / LC_TY, 64);  // 32 strips x 64 batches
    dim3 block(LC_NT);
    LocalConnectivity_kernel<<<grid, block, 0, stream>>>(grid_spikes, distance_weights, out);
}